// Round 21
// baseline (271.858 us; speedup 1.0000x reference)
//
#include <hip/hip_runtime.h>
#include <stdint.h>

#define T_SEQ 2048
#define NH 16
#define HD 128
#define CC 2048
#define N3 6144
#define MM 4096   // B*T

typedef short bf16x8 __attribute__((ext_vector_type(8)));
typedef float f32x4 __attribute__((ext_vector_type(4)));
typedef float f32x16 __attribute__((ext_vector_type(16)));
typedef unsigned int u32x4 __attribute__((ext_vector_type(4)));

__device__ __forceinline__ unsigned short f2bf(float f) {
  unsigned int u = __float_as_uint(f);
  u += 0x7FFF + ((u >> 16) & 1);   // RNE
  return (unsigned short)(u >> 16);
}
__device__ __forceinline__ float bf2f(unsigned short h) {
  return __uint_as_float(((unsigned int)h) << 16);
}
__device__ __forceinline__ unsigned int cvt_pk_bf16(float lo, float hi) {
  unsigned int r;
  asm("v_cvt_pk_bf16_f32 %0, %1, %2" : "=v"(r) : "v"(lo), "v"(hi));
  return r;
}

// ---------------- fused preprocessing: Wqkv^T, Wproj^T, x cvt, RoPE cos/sin table --------
// 1D grid 25088: [0,12288) Wqkv transpose, [12288,16384) Wproj, [16384,24576) x cvt,
// [24576,25088) RoPE table tbl[dd][t] (2048x64 float2, layout idx = dd*2048 + t).
__global__ __launch_bounds__(256) void k_prep(const float* __restrict__ Wqkv,
                                              unsigned short* __restrict__ WqkvT,
                                              const float* __restrict__ Wproj,
                                              unsigned short* __restrict__ WprojT,
                                              const float* __restrict__ x,
                                              unsigned short* __restrict__ xb,
                                              float2* __restrict__ tbl) {
  __shared__ float tile[32][33];
  const int bi = blockIdx.x;
  const int tx = threadIdx.x & 31, ty = threadIdx.x >> 5;
  if (bi < 16384) {
    const float* in;
    unsigned short* out;
    int k0, n0, N;
    if (bi < 12288) {
      in = Wqkv; out = WqkvT; N = N3;
      k0 = (bi & 63) * 32; n0 = (bi >> 6) * 32;
    } else {
      in = Wproj; out = WprojT; N = CC;
      int b2 = bi - 12288;
      k0 = (b2 & 63) * 32; n0 = (b2 >> 6) * 32;
    }
    #pragma unroll
    for (int r = ty; r < 32; r += 8)
      tile[r][tx] = in[(size_t)(k0 + r) * N + n0 + tx];
    __syncthreads();
    #pragma unroll
    for (int r = ty; r < 32; r += 8)
      out[(size_t)(n0 + r) * CC + k0 + tx] = f2bf(tile[tx][r]);
  } else if (bi < 24576) {
    int i = (bi - 16384) * 256 + threadIdx.x;   // over MM*CC/4
    float4 v = ((const float4*)x)[i];
    ushort4 o;
    o.x = f2bf(v.x); o.y = f2bf(v.y); o.z = f2bf(v.z); o.w = f2bf(v.w);
    ((ushort4*)xb)[i] = o;
  } else {
    int idx = (bi - 24576) * 256 + threadIdx.x;  // [0, 131072)
    int dd = idx >> 11;                          // pair index 0..63
    int t = idx & 2047;
    float invf = exp2f(-(float)dd * (13.287712379549449f / 64.f)); // 10000^(-dd/64)
    float ang = (float)t * invf;
    tbl[idx] = make_float2(cosf(ang), sinf(ang));
  }
}

// ---------------- bf16 GEMM, BM=128, BN=NJ*64 --------------------------------------------
// NJ==6: 8-phase schedule.  NJ==4: merged 4-phase.
// EPI==1: all outputs staged through LDS; q,k get TABLE-DRIVEN RoPE in the flush
// (q also scaled log2e/sqrt(D)); v stored transposed to vt (B,H,D,T) coalesced.
template<int NJ, int EPI, int MMAJ>
__global__ __launch_bounds__(512, 1) void k_gemm8(const unsigned short* __restrict__ A,
                                                  const unsigned short* __restrict__ Bt,
                                                  float* __restrict__ C,
                                                  unsigned short* __restrict__ qo,
                                                  unsigned short* __restrict__ ko,
                                                  unsigned short* __restrict__ vto,
                                                  const float2* __restrict__ tbl,
                                                  int M, int N, int K) {
  constexpr int BU = NJ / 2;             // B units of 128 rows
  constexpr int DSTRIDE = (1 + BU) * 16384;
  extern __shared__ __align__(16) char lds[];
  const int tid = threadIdx.x;
  const int lane = tid & 63;
  const int lr = lane & 15, lg = lane >> 4;
  const int wave = tid >> 6;
  const int wm = wave >> 2, wn = wave & 3;
  const int nwg = gridDim.x;
  const int bid = blockIdx.x;
  const int wg = (bid & 7) * (nwg >> 3) + (bid >> 3);
  const int GX = M >> 7;
  const int GN = N / (NJ * 64);
  const int mt = MMAJ ? (wg % GX) : (wg / GN);
  const int nt = MMAJ ? (wg / GX) : (wg % GN);
  const int m0 = mt * 128, n0 = nt * NJ * 64;
  const int NT = K >> 6;

  auto STAGE = [&](int d, int op, int h, int t) {
    const unsigned short* src = op ? Bt : A;
    const int r0 = (op ? n0 + h * 128 : m0);
    const int kc = t * 64;
    char* base = lds + d * DSTRIDE + op * 16384 + h * 16384;
    #pragma unroll
    for (int l = 0; l < 2; ++l) {
      int p = (l * 512 + tid) * 16;
      int qq = p ^ (((p >> 7) & 7) << 4);
      const unsigned short* g = src + (size_t)(r0 + (qq >> 7)) * K + kc + ((qq & 127) >> 1);
      __builtin_amdgcn_global_load_lds(
          (const __attribute__((address_space(1))) void*)g,
          (__attribute__((address_space(3))) void*)(base + (l * 512 + (tid & 448)) * 16),
          16, 0, 0);
    }
  };
  auto RD = [&](int d, int op, int row, int kb) -> bf16x8 {
    const char* base = lds + d * DSTRIDE + op * 16384;
    int p = row * 128 + kb;
    p ^= ((p >> 7) & 7) << 4;
    return *(const bf16x8*)(base + p);
  };

  f32x4 acc[4][NJ];
  #pragma unroll
  for (int i = 0; i < 4; ++i)
    #pragma unroll
    for (int j = 0; j < NJ; ++j) acc[i][j] = (f32x4){0.f, 0.f, 0.f, 0.f};

  bf16x8 bfrg[NJ][2];

// 8-phase single-mi phase (round-10)
#define GPH(D, MI, READB, DOST, SD, SO, SH, ST, VM)                                      \
  {                                                                                      \
    if (READB) {                                                                         \
      _Pragma("unroll")                                                                  \
      for (int nj = 0; nj < NJ; ++nj)                                                    \
        _Pragma("unroll")                                                                \
        for (int ks = 0; ks < 2; ++ks)                                                   \
          bfrg[nj][ks] = RD(D, 1, wn * NJ * 16 + nj * 16 + lr, ks * 64 + lg * 16);       \
    }                                                                                    \
    bf16x8 af[2];                                                                        \
    _Pragma("unroll")                                                                    \
    for (int ks = 0; ks < 2; ++ks)                                                       \
      af[ks] = RD(D, 0, wm * 64 + (MI) * 16 + lr, ks * 64 + lg * 16);                    \
    if (DOST) STAGE(SD, SO, SH, ST);                                                     \
    __builtin_amdgcn_s_barrier();                                                        \
    asm volatile("s_waitcnt lgkmcnt(0)" ::: "memory");                                   \
    __builtin_amdgcn_s_setprio(1);                                                       \
    _Pragma("unroll")                                                                    \
    for (int nj = 0; nj < NJ; ++nj)                                                      \
      _Pragma("unroll")                                                                  \
      for (int ks = 0; ks < 2; ++ks)                                                     \
        acc[MI][nj] = __builtin_amdgcn_mfma_f32_16x16x32_bf16(af[ks], bfrg[nj][ks], acc[MI][nj], 0, 0, 0); \
    __builtin_amdgcn_s_setprio(0);                                                       \
    if ((VM) == 6) asm volatile("s_waitcnt vmcnt(6)" ::: "memory");                      \
    if ((VM) == 4) asm volatile("s_waitcnt vmcnt(4)" ::: "memory");                      \
    __builtin_amdgcn_s_barrier();                                                        \
  }

// merged 2-mi phase (round-11)
#define GPM(D, MIB, READB, VM, ...)                                                      \
  {                                                                                      \
    if (READB) {                                                                         \
      _Pragma("unroll")                                                                  \
      for (int nj = 0; nj < NJ; ++nj)                                                    \
        _Pragma("unroll")                                                                \
        for (int ks = 0; ks < 2; ++ks)                                                   \
          bfrg[nj][ks] = RD(D, 1, wn * NJ * 16 + nj * 16 + lr, ks * 64 + lg * 16);       \
    }                                                                                    \
    bf16x8 af2[2][2];                                                                    \
    _Pragma("unroll")                                                                    \
    for (int mm = 0; mm < 2; ++mm)                                                       \
      _Pragma("unroll")                                                                  \
      for (int ks = 0; ks < 2; ++ks)                                                     \
        af2[mm][ks] = RD(D, 0, wm * 64 + (MIB + mm) * 16 + lr, ks * 64 + lg * 16);       \
    __VA_ARGS__                                                                          \
    __builtin_amdgcn_s_barrier();                                                        \
    asm volatile("s_waitcnt lgkmcnt(0)" ::: "memory");                                   \
    __builtin_amdgcn_s_setprio(1);                                                       \
    _Pragma("unroll")                                                                    \
    for (int mm = 0; mm < 2; ++mm)                                                       \
      _Pragma("unroll")                                                                  \
      for (int nj = 0; nj < NJ; ++nj)                                                    \
        _Pragma("unroll")                                                                \
        for (int ks = 0; ks < 2; ++ks)                                                   \
          acc[MIB + mm][nj] = __builtin_amdgcn_mfma_f32_16x16x32_bf16(af2[mm][ks], bfrg[nj][ks], acc[MIB + mm][nj], 0, 0, 0); \
    __builtin_amdgcn_s_setprio(0);                                                       \
    if ((VM) == 4) asm volatile("s_waitcnt vmcnt(4)" ::: "memory");                      \
    if ((VM) == 2) asm volatile("s_waitcnt vmcnt(2)" ::: "memory");                      \
    __builtin_amdgcn_s_barrier();                                                        \
  }

  const int t1 = NT > 1 ? 1 : 0;
  #pragma unroll
  for (int h = 0; h < BU; ++h) STAGE(0, 1, h, 0);
  STAGE(0, 0, 0, 0);
  #pragma unroll
  for (int h = 0; h < BU; ++h) STAGE(1, 1, h, t1);
  if (NJ == 6) asm volatile("s_waitcnt vmcnt(6)" ::: "memory");
  else         asm volatile("s_waitcnt vmcnt(4)" ::: "memory");
  __builtin_amdgcn_s_barrier();

  for (int it = 0; it < (NT >> 1); ++it) {
    const int tb  = 2 * it + 1;
    const int ta1 = min(2 * it + 2, NT - 1);
    const int tb1 = min(2 * it + 3, NT - 1);
    if constexpr (NJ == 6) {
      GPH(0, 0, true,  true, 1, 0, 0, tb,  -1)
      GPH(0, 1, false, true, 0, 1, 0, ta1, -1)
      GPH(0, 2, false, true, 0, 1, 1, ta1, -1)
      GPH(0, 3, false, true, 0, 1, 2, ta1,  6)
      GPH(1, 0, true,  true, 0, 0, 0, ta1, -1)
      GPH(1, 1, false, true, 1, 1, 0, tb1, -1)
      GPH(1, 2, false, true, 1, 1, 1, tb1, -1)
      GPH(1, 3, false, true, 1, 1, 2, tb1,  6)
    } else {
      GPM(0, 0, true,  -1, STAGE(1, 0, 0, tb);)
      GPM(0, 2, false,  2, STAGE(0, 1, 0, ta1);)
      GPM(1, 0, true,  -1, STAGE(0, 1, 1, ta1); STAGE(0, 0, 0, ta1);)
      GPM(1, 2, false,  4, STAGE(1, 1, 0, tb1); STAGE(1, 1, 1, tb1);)
    }
  }
#undef GPH
#undef GPM

  if (EPI == 0) {
    #pragma unroll
    for (int mi = 0; mi < 4; ++mi)
      #pragma unroll
      for (int nj = 0; nj < NJ; ++nj)
        #pragma unroll
        for (int j = 0; j < 4; ++j) {
          int m = m0 + wm * 64 + mi * 16 + lg * 4 + j;
          int n = n0 + wn * NJ * 16 + nj * 16 + lr;
          C[(size_t)m * N + n] = acc[mi][nj][j];
        }
  } else {
    // stage ALL 384 columns through dead main-loop LDS, then flush:
    //   v -> coalesced transposed stores; q/k -> table-driven RoPE then scatter.
    __builtin_amdgcn_s_barrier();                 // main-loop LDS reads done
    unsigned short* ldv = (unsigned short*)lds;   // [col][136] shorts
    #pragma unroll
    for (int mi = 0; mi < 4; ++mi) {
      #pragma unroll
      for (int nj = 0; nj < NJ; ++nj) {
        int lcol = wn * NJ * 16 + nj * 16 + lr;
        int lrow = wm * 64 + mi * 16 + lg * 4;
        #pragma unroll
        for (int j = 0; j < 4; ++j)
          ldv[lcol * 136 + lrow + j] = f2bf(acc[mi][nj][j]);
      }
    }
    __builtin_amdgcn_s_barrier();
    const int bb = m0 >> 11, t0 = m0 & 2047;
    for (int pass = 0; pass < (NJ * 64) / 32; ++pass) {
      int col = pass * 32 + (tid >> 4);
      int rg = tid & 15;
      int n = n0 + col;
      int which = n >> 11;
      int cc = n & 2047, h = cc >> 7, d = cc & 127;
      if (which == 2) {
        bf16x8 vv = *(const bf16x8*)(ldv + col * 136 + rg * 8);
        *(bf16x8*)(vto + (((size_t)(bb * NH + h) * HD + d) * T_SEQ + t0 + rg * 8)) = vv;
      } else {
        int dd = d & 63;
        int colp = (d < 64) ? col + 64 : col - 64;   // pair stays in-window & same tensor
        float sign = (d < 64) ? -1.f : 1.f;
        float scl = (which == 0) ? 0.12751741562076117f : 1.0f;  // log2e/sqrt(128) on q
        unsigned short* dst = (which == 0) ? qo : ko;
        bf16x8 ow = *(const bf16x8*)(ldv + col * 136 + rg * 8);
        bf16x8 pr = *(const bf16x8*)(ldv + colp * 136 + rg * 8);
        size_t dbase = ((size_t)(bb * NH + h) * T_SEQ + t0 + rg * 8) * HD + d;
        #pragma unroll
        for (int j = 0; j < 8; ++j) {
          float2 cs = tbl[(dd << 11) + t0 + rg * 8 + j];
          float o = bf2f((unsigned short)ow[j]);
          float p = bf2f((unsigned short)pr[j]);
          dst[dbase + (size_t)j * HD] = f2bf((o * cs.x + sign * p * cs.y) * scl);
        }
      }
    }
  }
}

// ---------------- causal flash attention: parity-split KV, 8 waves, LSE merge ------------
// (round-15 passing structure, unchanged; q pre-roped+scaled, k pre-roped by GEMM1)
__global__ __launch_bounds__(512, 1) void k_attn(const unsigned short* __restrict__ Q,
                                                 const unsigned short* __restrict__ K,
                                                 const unsigned short* __restrict__ Vt,
                                                 unsigned short* __restrict__ Y) {
  extern __shared__ __align__(16) char alds[];
  char* Kls = alds;              // 4 x 16KB
  char* Vls = alds + 65536;      // 4 x 16KB
  const int id = blockIdx.x;             // 0..511
  const int bh = id & 31;
  const int qtl = 15 - (id >> 5);        // heavy first (LPT)
  const int b = bh >> 4, h = bh & 15;
  const int tid = threadIdx.x, wv = tid >> 6, lane = tid & 63;
  const int l31 = lane & 31, hh = lane >> 5;
  const int par = wv >> 2;               // 0: even jt, 1: odd jt
  const int wq = wv & 3;
  const int q0 = qtl * 128;
  const int qglob = q0 + wq * 32 + l31;
  const unsigned short* Qb = Q + (size_t)bh * T_SEQ * HD;
  const unsigned short* Kb = K + (size_t)bh * T_SEQ * HD;
  const unsigned short* Vb = Vt + (size_t)bh * HD * T_SEQ;

  auto STAGEK = [&](int tk, int s) {
    char* base = Kls + s * 16384;
    #pragma unroll
    for (int ch = 0; ch < 2; ++ch) {
      int p = (ch * 512 + tid) * 16;
      int q = p ^ (((p >> 8) & 7) << 4);
      const unsigned short* g = Kb + (size_t)(tk + (q >> 8)) * HD + ((q & 255) >> 1);
      __builtin_amdgcn_global_load_lds(
          (const __attribute__((address_space(1))) void*)g,
          (__attribute__((address_space(3))) void*)(base + (ch * 512 + (tid & 448)) * 16),
          16, 0, 0);
    }
  };
  auto STAGEV = [&](int tk, int s) {
    char* base = Vls + s * 16384;
    #pragma unroll
    for (int ch = 0; ch < 2; ++ch) {
      int p = (ch * 512 + tid) * 16;
      int q = p ^ (((p >> 7) & 7) << 4);
      const unsigned short* g = Vb + (size_t)(q >> 7) * T_SEQ + tk + ((q & 127) >> 1);
      __builtin_amdgcn_global_load_lds(
          (const __attribute__((address_space(1))) void*)g,
          (__attribute__((address_space(3))) void*)(base + (ch * 512 + (tid & 448)) * 16),
          16, 0, 0);
    }
  };

  // hoist Q (pre-roped, pre-scaled)
  bf16x8 qfr[8];
  #pragma unroll
  for (int c = 0; c < 8; ++c)
    qfr[c] = *(const bf16x8*)(Qb + (size_t)qglob * HD + c * 16 + hh * 8);

  f32x16 oacc[4];
  #pragma unroll
  for (int dt = 0; dt < 4; ++dt)
    #pragma unroll
    for (int r = 0; r < 16; ++r) oacc[dt][r] = 0.f;
  float mrun = -1e30f, lrun = 0.f;

  // prologue: tiles 0,1 -> slots 0,1
  STAGEK(0, 0); STAGEV(0, 0);
  STAGEK(64, 1); STAGEV(64, 1);
  asm volatile("s_waitcnt vmcnt(0)" ::: "memory");
  __syncthreads();

  for (int u = 0; u <= qtl; ++u) {
    if (u < qtl) {
      STAGEK((2 * u + 2) * 64, (2 * u + 2) & 3); STAGEV((2 * u + 2) * 64, (2 * u + 2) & 3);
      STAGEK((2 * u + 3) * 64, (2 * u + 3) & 3); STAGEV((2 * u + 3) * 64, (2 * u + 3) & 3);
    }
    const int jt = 2 * u + par;
    const int slot = jt & 3;

    // QK: S^T = K Q^T  (batched reads: 8 kf then 8 MFMA per t-chain)
    f32x16 sacc[2];
    #pragma unroll
    for (int t = 0; t < 2; ++t)
      #pragma unroll
      for (int r = 0; r < 16; ++r) sacc[t][r] = 0.f;
    {
      const char* kbase = Kls + slot * 16384;
      #pragma unroll
      for (int t = 0; t < 2; ++t) {
        bf16x8 kf8[8];
        #pragma unroll
        for (int s = 0; s < 8; ++s) {
          int row = t * 32 + l31;
          int byte = (row * 256 + s * 32 + hh * 16) ^ ((row & 7) << 4);
          kf8[s] = *(const bf16x8*)(kbase + byte);
        }
        __builtin_amdgcn_s_setprio(1);
        #pragma unroll
        for (int s = 0; s < 8; ++s)
          sacc[t] = __builtin_amdgcn_mfma_f32_32x32x16_bf16(kf8[s], qfr[s], sacc[t], 0, 0, 0);
        __builtin_amdgcn_s_setprio(0);
      }
    }

    if (jt >= 2 * qtl) {
      #pragma unroll
      for (int t = 0; t < 2; ++t)
        #pragma unroll
        for (int r = 0; r < 16; ++r) {
          int kg = jt * 64 + t * 32 + (r & 3) + 8 * (r >> 2) + 4 * hh;
          if (kg > qglob) sacc[t][r] = -1e30f;
        }
    }

    float pmax = sacc[0][0];
    #pragma unroll
    for (int r = 1; r < 16; ++r) pmax = fmaxf(pmax, sacc[0][r]);
    #pragma unroll
    for (int r = 0; r < 16; ++r) pmax = fmaxf(pmax, sacc[1][r]);
    pmax = fmaxf(pmax, __shfl_xor(pmax, 32));

    if (__any(pmax > mrun + 8.0f)) {   // defer-max (T13)
      float mnew = fmaxf(mrun, pmax);
      float osc = exp2f(mrun - mnew);
      lrun *= osc;
      mrun = mnew;
      #pragma unroll
      for (int r = 0; r < 16; ++r) {
        int qr = (r & 3) + 8 * (r >> 2) + 4 * hh;
        float sr = __shfl(osc, qr);
        #pragma unroll
        for (int dt = 0; dt < 4; ++dt) oacc[dt][r] *= sr;
      }
    }

    unsigned int pk[16];
    float rsum = 0.f;
    #pragma unroll
    for (int t = 0; t < 2; ++t)
      #pragma unroll
      for (int i = 0; i < 8; ++i) {
        float p0 = exp2f(sacc[t][2 * i] - mrun);
        float p1 = exp2f(sacc[t][2 * i + 1] - mrun);
        rsum += p0 + p1;
        pk[t * 8 + i] = cvt_pk_bf16(p0, p1);
      }
    rsum += __shfl_xor(rsum, 32);
    lrun += rsum;

    bf16x8 pa[4];
    #pragma unroll
    for (int c = 0; c < 4; ++c) {
      int base = (c >> 1) * 8 + (c & 1) * 4;
      unsigned int s0 = hh == 0 ? pk[base + 2] : pk[base + 0];
      unsigned int s1 = hh == 0 ? pk[base + 3] : pk[base + 1];
      unsigned int r0 = __shfl_xor((int)s0, 32);
      unsigned int r1 = __shfl_xor((int)s1, 32);
      u32x4 f;
      f[0] = hh == 0 ? pk[base + 0] : r0;
      f[1] = hh == 0 ? pk[base + 1] : r1;
      f[2] = hh == 0 ? r0 : pk[base + 2];
      f[3] = hh == 0 ? r1 : pk[base + 3];
      pa[c] = *(bf16x8*)&f;
    }

    {
      const char* vbase = Vls + slot * 16384;
      __builtin_amdgcn_s_setprio(1);
      #pragma unroll
      for (int dt = 0; dt < 4; ++dt) {
        #pragma unroll
        for (int c = 0; c < 4; ++c) {
          int row = dt * 32 + l31;
          int byte = (row * 128 + c * 32 + hh * 16) ^ ((row & 7) << 4);
          bf16x8 vf = *(const bf16x8*)(vbase + byte);
          oacc[dt] = __builtin_amdgcn_mfma_f32_32x32x16_bf16(pa[c], vf, oacc[dt], 0, 0, 0);
        }
      }
      __builtin_amdgcn_s_setprio(0);
    }

    asm volatile("s_waitcnt vmcnt(0)" ::: "memory");
    __syncthreads();
  }

  // ---- merge the two parity streams (exact LSE); buffers in DEAD K/V regions ----
  float* obuf  = (float*)alds;
  float* mlbuf = (float*)(alds + 65536);
  if (par == 1) {
    mlbuf[(wq * 64 + lane) * 2 + 0] = mrun;
    mlbuf[(wq * 64 + lane) * 2 + 1] = lrun;
    float* ob = obuf + wq * 4096;
    #pragma unroll
    for (int dt = 0; dt < 4; ++dt)
      #pragma unroll
      for (int r = 0; r < 16; ++r)
        ob[(dt * 16 + r) * 64 + lane] = oacc[dt][r];
  }
  __syncthreads();
  if (par == 0) {
    float mo = mlbuf[(wq * 64 + lane) * 2 + 0];
    float lo = mlbuf[(wq * 64 + lane) * 2 + 1];
    float mm = fmaxf(mrun, mo);
    float se = exp2f(mrun - mm), so = exp2f(mo - mm);
    float lt = lrun * se + lo * so;
    float linv = 1.0f / lt;
    const float* ob = obuf + wq * 4096;
    #pragma unroll
    for (int r = 0; r < 16; ++r) {
      int qr = (r & 3) + 8 * (r >> 2) + 4 * hh;
      float se_r = __shfl(se, qr);
      float so_r = __shfl(so, qr);
      float li_r = __shfl(linv, qr);
      int qg = q0 + wq * 32 + qr;
      size_t base = ((size_t)b * T_SEQ + qg) * CC + h * HD;
      #pragma unroll
      for (int dt = 0; dt < 4; ++dt) {
        float oo = ob[(dt * 16 + r) * 64 + lane];
        Y[base + dt * 32 + l31] = f2bf((oacc[dt][r] * se_r + oo * so_r) * li_r);
      }
    }
  }
}

extern "C" void kernel_launch(void* const* d_in, const int* in_sizes, int n_in,
                              void* d_out, int out_size, void* d_ws, size_t ws_size,
                              hipStream_t stream) {
  const float* x     = (const float*)d_in[0];
  const float* Wqkv  = (const float*)d_in[1];
  const float* Wproj = (const float*)d_in[2];
  float* out = (float*)d_out;
  char* ws = (char*)d_ws;
  const size_t MB = 1024 * 1024;
  unsigned short* WqkvT  = (unsigned short*)(ws + 0);        // 24MB; live during GEMM1
  unsigned short* WprojT = (unsigned short*)(ws + 24 * MB);  // 8MB
  unsigned short* xb     = (unsigned short*)(ws + 32 * MB);  // 16MB; dead after GEMM1
  unsigned short* y      = xb;                               // aliases xb
  unsigned short* q      = (unsigned short*)(ws + 48 * MB);  // 16MB
  unsigned short* k      = (unsigned short*)(ws + 64 * MB);  // 16MB
  unsigned short* vt     = (unsigned short*)(ws + 80 * MB);  // 16MB, written by GEMM1
  // RoPE cos/sin table lives in d_out's first 1MB (dead until GEMM2 overwrites all of out)
  float2* tbl = (float2*)d_out;

  k_prep<<<dim3(25088), 256, 0, stream>>>(Wqkv, WqkvT, Wproj, WprojT, x, xb, tbl);
  // GEMM1: 4096 x 6144 x 2048, BM=128 BN=384 -> grid 512 (exactly 2 gens), m-major chunks
  k_gemm8<6, 1, 1><<<dim3((MM / 128) * (N3 / 384)), 512, 131072, stream>>>(
      xb, WqkvT, nullptr, q, k, vt, tbl, MM, N3, CC);
  k_attn<<<dim3(512), 512, 131072, stream>>>(q, k, vt, y);
  // GEMM2: 4096 x 2048 x 2048, BM=128 BN=256 -> grid 256 (exactly 1/CU), n-major chunks
  k_gemm8<4, 0, 0><<<dim3((MM / 128) * (CC / 256)), 512, 98304, stream>>>(
      y, WprojT, out, nullptr, nullptr, nullptr, nullptr, MM, CC, CC);
}

// Round 22
// 247.839 us; speedup vs baseline: 1.0969x; 1.0969x over previous
//
#include <hip/hip_runtime.h>
#include <stdint.h>

#define T_SEQ 2048
#define NH 16
#define HD 128
#define CC 2048
#define N3 6144
#define MM 4096   // B*T

typedef short bf16x8 __attribute__((ext_vector_type(8)));
typedef float f32x4 __attribute__((ext_vector_type(4)));
typedef float f32x16 __attribute__((ext_vector_type(16)));
typedef unsigned int u32x4 __attribute__((ext_vector_type(4)));

__device__ __forceinline__ unsigned short f2bf(float f) {
  unsigned int u = __float_as_uint(f);
  u += 0x7FFF + ((u >> 16) & 1);   // RNE
  return (unsigned short)(u >> 16);
}
__device__ __forceinline__ float bf2f(unsigned short h) {
  return __uint_as_float(((unsigned int)h) << 16);
}
__device__ __forceinline__ unsigned int cvt_pk_bf16(float lo, float hi) {
  unsigned int r;
  asm("v_cvt_pk_bf16_f32 %0, %1, %2" : "=v"(r) : "v"(lo), "v"(hi));
  return r;
}

// ---------------- fused preprocessing: Wqkv^T, Wproj^T (fp32->bf16), x cvt --------------
// 1D grid 24576: [0,12288) Wqkv transpose (32x32 tiles), [12288,16384) Wproj,
// [16384,24576) x float4->bf16x4 cvt.
__global__ __launch_bounds__(256) void k_prep(const float* __restrict__ Wqkv,
                                              unsigned short* __restrict__ WqkvT,
                                              const float* __restrict__ Wproj,
                                              unsigned short* __restrict__ WprojT,
                                              const float* __restrict__ x,
                                              unsigned short* __restrict__ xb) {
  __shared__ float tile[32][33];
  const int bi = blockIdx.x;
  const int tx = threadIdx.x & 31, ty = threadIdx.x >> 5;
  if (bi < 16384) {
    const float* in;
    unsigned short* out;
    int k0, n0, N;
    if (bi < 12288) {
      in = Wqkv; out = WqkvT; N = N3;
      k0 = (bi & 63) * 32; n0 = (bi >> 6) * 32;
    } else {
      in = Wproj; out = WprojT; N = CC;
      int b2 = bi - 12288;
      k0 = (b2 & 63) * 32; n0 = (b2 >> 6) * 32;
    }
    #pragma unroll
    for (int r = ty; r < 32; r += 8)
      tile[r][tx] = in[(size_t)(k0 + r) * N + n0 + tx];
    __syncthreads();
    #pragma unroll
    for (int r = ty; r < 32; r += 8)
      out[(size_t)(n0 + r) * CC + k0 + tx] = f2bf(tile[tx][r]);
  } else {
    int i = (bi - 16384) * 256 + threadIdx.x;   // over MM*CC/4
    float4 v = ((const float4*)x)[i];
    ushort4 o;
    o.x = f2bf(v.x); o.y = f2bf(v.y); o.z = f2bf(v.z); o.w = f2bf(v.w);
    ((ushort4*)xb)[i] = o;
  }
}

// ---------------- bf16 GEMM, BM=128, BN=NJ*64 --------------------------------------------
// NJ==6: 8-phase schedule (round-10, 109.7us).  NJ==4: merged 4-phase (round-11).
// EPI==1: q,k scattered (B,H,T,D); v written TRANSPOSED to vt (B,H,D,T) via an LDS
// re-tile in the epilogue (256B contiguous stores).
template<int NJ, int EPI, int MMAJ>
__global__ __launch_bounds__(512, 1) void k_gemm8(const unsigned short* __restrict__ A,
                                                  const unsigned short* __restrict__ Bt,
                                                  float* __restrict__ C,
                                                  unsigned short* __restrict__ qo,
                                                  unsigned short* __restrict__ ko,
                                                  unsigned short* __restrict__ vto,
                                                  int M, int N, int K) {
  constexpr int BU = NJ / 2;             // B units of 128 rows
  constexpr int DSTRIDE = (1 + BU) * 16384;
  extern __shared__ __align__(16) char lds[];
  const int tid = threadIdx.x;
  const int lane = tid & 63;
  const int lr = lane & 15, lg = lane >> 4;
  const int wave = tid >> 6;
  const int wm = wave >> 2, wn = wave & 3;
  const int nwg = gridDim.x;
  const int bid = blockIdx.x;
  const int wg = (bid & 7) * (nwg >> 3) + (bid >> 3);
  const int GX = M >> 7;
  const int GN = N / (NJ * 64);
  const int mt = MMAJ ? (wg % GX) : (wg / GN);
  const int nt = MMAJ ? (wg / GX) : (wg % GN);
  const int m0 = mt * 128, n0 = nt * NJ * 64;
  const int NT = K >> 6;

  auto STAGE = [&](int d, int op, int h, int t) {
    const unsigned short* src = op ? Bt : A;
    const int r0 = (op ? n0 + h * 128 : m0);
    const int kc = t * 64;
    char* base = lds + d * DSTRIDE + op * 16384 + h * 16384;
    #pragma unroll
    for (int l = 0; l < 2; ++l) {
      int p = (l * 512 + tid) * 16;
      int qq = p ^ (((p >> 7) & 7) << 4);
      const unsigned short* g = src + (size_t)(r0 + (qq >> 7)) * K + kc + ((qq & 127) >> 1);
      __builtin_amdgcn_global_load_lds(
          (const __attribute__((address_space(1))) void*)g,
          (__attribute__((address_space(3))) void*)(base + (l * 512 + (tid & 448)) * 16),
          16, 0, 0);
    }
  };
  auto RD = [&](int d, int op, int row, int kb) -> bf16x8 {
    const char* base = lds + d * DSTRIDE + op * 16384;
    int p = row * 128 + kb;
    p ^= ((p >> 7) & 7) << 4;
    return *(const bf16x8*)(base + p);
  };

  f32x4 acc[4][NJ];
  #pragma unroll
  for (int i = 0; i < 4; ++i)
    #pragma unroll
    for (int j = 0; j < NJ; ++j) acc[i][j] = (f32x4){0.f, 0.f, 0.f, 0.f};

  bf16x8 bfrg[NJ][2];

// 8-phase single-mi phase (round-10)
#define GPH(D, MI, READB, DOST, SD, SO, SH, ST, VM)                                      \
  {                                                                                      \
    if (READB) {                                                                         \
      _Pragma("unroll")                                                                  \
      for (int nj = 0; nj < NJ; ++nj)                                                    \
        _Pragma("unroll")                                                                \
        for (int ks = 0; ks < 2; ++ks)                                                   \
          bfrg[nj][ks] = RD(D, 1, wn * NJ * 16 + nj * 16 + lr, ks * 64 + lg * 16);       \
    }                                                                                    \
    bf16x8 af[2];                                                                        \
    _Pragma("unroll")                                                                    \
    for (int ks = 0; ks < 2; ++ks)                                                       \
      af[ks] = RD(D, 0, wm * 64 + (MI) * 16 + lr, ks * 64 + lg * 16);                    \
    if (DOST) STAGE(SD, SO, SH, ST);                                                     \
    __builtin_amdgcn_s_barrier();                                                        \
    asm volatile("s_waitcnt lgkmcnt(0)" ::: "memory");                                   \
    __builtin_amdgcn_s_setprio(1);                                                       \
    _Pragma("unroll")                                                                    \
    for (int nj = 0; nj < NJ; ++nj)                                                      \
      _Pragma("unroll")                                                                  \
      for (int ks = 0; ks < 2; ++ks)                                                     \
        acc[MI][nj] = __builtin_amdgcn_mfma_f32_16x16x32_bf16(af[ks], bfrg[nj][ks], acc[MI][nj], 0, 0, 0); \
    __builtin_amdgcn_s_setprio(0);                                                       \
    if ((VM) == 6) asm volatile("s_waitcnt vmcnt(6)" ::: "memory");                      \
    if ((VM) == 4) asm volatile("s_waitcnt vmcnt(4)" ::: "memory");                      \
    __builtin_amdgcn_s_barrier();                                                        \
  }

// merged 2-mi phase (round-11)
#define GPM(D, MIB, READB, VM, ...)                                                      \
  {                                                                                      \
    if (READB) {                                                                         \
      _Pragma("unroll")                                                                  \
      for (int nj = 0; nj < NJ; ++nj)                                                    \
        _Pragma("unroll")                                                                \
        for (int ks = 0; ks < 2; ++ks)                                                   \
          bfrg[nj][ks] = RD(D, 1, wn * NJ * 16 + nj * 16 + lr, ks * 64 + lg * 16);       \
    }                                                                                    \
    bf16x8 af2[2][2];                                                                    \
    _Pragma("unroll")                                                                    \
    for (int mm = 0; mm < 2; ++mm)                                                       \
      _Pragma("unroll")                                                                  \
      for (int ks = 0; ks < 2; ++ks)                                                     \
        af2[mm][ks] = RD(D, 0, wm * 64 + (MIB + mm) * 16 + lr, ks * 64 + lg * 16);       \
    __VA_ARGS__                                                                          \
    __builtin_amdgcn_s_barrier();                                                        \
    asm volatile("s_waitcnt lgkmcnt(0)" ::: "memory");                                   \
    __builtin_amdgcn_s_setprio(1);                                                       \
    _Pragma("unroll")                                                                    \
    for (int mm = 0; mm < 2; ++mm)                                                       \
      _Pragma("unroll")                                                                  \
      for (int nj = 0; nj < NJ; ++nj)                                                    \
        _Pragma("unroll")                                                                \
        for (int ks = 0; ks < 2; ++ks)                                                   \
          acc[MIB + mm][nj] = __builtin_amdgcn_mfma_f32_16x16x32_bf16(af2[mm][ks], bfrg[nj][ks], acc[MIB + mm][nj], 0, 0, 0); \
    __builtin_amdgcn_s_setprio(0);                                                       \
    if ((VM) == 4) asm volatile("s_waitcnt vmcnt(4)" ::: "memory");                      \
    if ((VM) == 2) asm volatile("s_waitcnt vmcnt(2)" ::: "memory");                      \
    __builtin_amdgcn_s_barrier();                                                        \
  }

  const int t1 = NT > 1 ? 1 : 0;
  #pragma unroll
  for (int h = 0; h < BU; ++h) STAGE(0, 1, h, 0);
  STAGE(0, 0, 0, 0);
  #pragma unroll
  for (int h = 0; h < BU; ++h) STAGE(1, 1, h, t1);
  if (NJ == 6) asm volatile("s_waitcnt vmcnt(6)" ::: "memory");
  else         asm volatile("s_waitcnt vmcnt(4)" ::: "memory");
  __builtin_amdgcn_s_barrier();

  for (int it = 0; it < (NT >> 1); ++it) {
    const int tb  = 2 * it + 1;
    const int ta1 = min(2 * it + 2, NT - 1);
    const int tb1 = min(2 * it + 3, NT - 1);
    if constexpr (NJ == 6) {
      GPH(0, 0, true,  true, 1, 0, 0, tb,  -1)
      GPH(0, 1, false, true, 0, 1, 0, ta1, -1)
      GPH(0, 2, false, true, 0, 1, 1, ta1, -1)
      GPH(0, 3, false, true, 0, 1, 2, ta1,  6)
      GPH(1, 0, true,  true, 0, 0, 0, ta1, -1)
      GPH(1, 1, false, true, 1, 1, 0, tb1, -1)
      GPH(1, 2, false, true, 1, 1, 1, tb1, -1)
      GPH(1, 3, false, true, 1, 1, 2, tb1,  6)
    } else {
      GPM(0, 0, true,  -1, STAGE(1, 0, 0, tb);)
      GPM(0, 2, false,  2, STAGE(0, 1, 0, ta1);)
      GPM(1, 0, true,  -1, STAGE(0, 1, 1, ta1); STAGE(0, 0, 0, ta1);)
      GPM(1, 2, false,  4, STAGE(1, 1, 0, tb1); STAGE(1, 1, 1, tb1);)
    }
  }
#undef GPH
#undef GPM

  if (EPI == 0) {
    #pragma unroll
    for (int mi = 0; mi < 4; ++mi)
      #pragma unroll
      for (int nj = 0; nj < NJ; ++nj)
        #pragma unroll
        for (int j = 0; j < 4; ++j) {
          int m = m0 + wm * 64 + mi * 16 + lg * 4 + j;
          int n = n0 + wn * NJ * 16 + nj * 16 + lr;
          C[(size_t)m * N + n] = acc[mi][nj][j];
        }
  } else {
    // q/k direct; v re-tiled through LDS for coalesced transposed stores.
    const bool hasV = (n0 + NJ * 64 > 4096);
    if (hasV) __builtin_amdgcn_s_barrier();   // main-loop LDS now dead
    unsigned short* ldv = (unsigned short*)lds;   // [col][136] shorts (pad -> 16B rows)
    #pragma unroll
    for (int mi = 0; mi < 4; ++mi) {
      #pragma unroll
      for (int nj = 0; nj < NJ; ++nj) {
        int lcol = wn * NJ * 16 + nj * 16 + lr;
        int n = n0 + lcol;
        int which = n >> 11, cc = n & 2047;
        int h = cc >> 7, d = cc & 127;
        int lrow = wm * 64 + mi * 16 + lg * 4;
        int m_base = m0 + lrow;
        int b = m_base >> 11, t = m_base & 2047;
        if (which == 2) {
          #pragma unroll
          for (int j = 0; j < 4; ++j)
            ldv[lcol * 136 + lrow + j] = f2bf(acc[mi][nj][j]);
        } else {
          unsigned short* dst = which == 0 ? qo : ko;
          #pragma unroll
          for (int j = 0; j < 4; ++j)
            dst[(((size_t)(b * NH + h)) * T_SEQ + t + j) * HD + d] = f2bf(acc[mi][nj][j]);
        }
      }
    }
    if (hasV) {
      __builtin_amdgcn_s_barrier();
      const int bb = m0 >> 11, t0 = m0 & 2047;
      for (int pass = 0; pass < (NJ * 64) / 32; ++pass) {
        int col = pass * 32 + (tid >> 4);
        int rg = tid & 15;
        int n = n0 + col;
        if ((n >> 11) == 2) {
          int cc = n & 2047, h = cc >> 7, d = cc & 127;
          bf16x8 vv = *(const bf16x8*)(ldv + col * 136 + rg * 8);
          *(bf16x8*)(vto + (((size_t)(bb * NH + h) * HD + d) * T_SEQ + t0 + rg * 8)) = vv;
        }
      }
    }
  }
}

// ---------------- RoPE in place on q (scaled by log2e/sqrt(D)) and k ----------------
__global__ __launch_bounds__(256) void k_rope(unsigned short* __restrict__ q,
                                              unsigned short* __restrict__ k) {
  int i = blockIdx.x * 256 + threadIdx.x;   // over 32 * 2048 * 64
  int d = i & 63;
  int t = (i >> 6) & (T_SEQ - 1);
  int bh = i >> 17;
  float invf = exp2f((float)(-2 * d) * (13.287712379549449f / 128.f)); // 10000^(-2d/128)
  float ang = (float)t * invf;
  float c = cosf(ang), s = sinf(ang);
  size_t base = ((size_t)bh * T_SEQ + t) * HD + d;
  const float scale = 0.12751741562076117f;  // log2(e)/sqrt(128): attn uses exp2
  float q1 = bf2f(q[base]), q2 = bf2f(q[base + 64]);
  q[base]      = f2bf((q1 * c - q2 * s) * scale);
  q[base + 64] = f2bf((q2 * c + q1 * s) * scale);
  float k1 = bf2f(k[base]), k2 = bf2f(k[base + 64]);
  k[base]      = f2bf(k1 * c - k2 * s);
  k[base + 64] = f2bf(k2 * c + k1 * s);
}

// ---------------- causal flash attention: parity-split KV, 8 waves, LSE merge ------------
// (round-15 passing structure, unchanged)
__global__ __launch_bounds__(512, 1) void k_attn(const unsigned short* __restrict__ Q,
                                                 const unsigned short* __restrict__ K,
                                                 const unsigned short* __restrict__ Vt,
                                                 unsigned short* __restrict__ Y) {
  extern __shared__ __align__(16) char alds[];
  char* Kls = alds;              // 4 x 16KB
  char* Vls = alds + 65536;      // 4 x 16KB
  const int id = blockIdx.x;             // 0..511
  const int bh = id & 31;
  const int qtl = 15 - (id >> 5);        // heavy first (LPT)
  const int b = bh >> 4, h = bh & 15;
  const int tid = threadIdx.x, wv = tid >> 6, lane = tid & 63;
  const int l31 = lane & 31, hh = lane >> 5;
  const int par = wv >> 2;               // 0: even jt, 1: odd jt
  const int wq = wv & 3;
  const int q0 = qtl * 128;
  const int qglob = q0 + wq * 32 + l31;
  const unsigned short* Qb = Q + (size_t)bh * T_SEQ * HD;
  const unsigned short* Kb = K + (size_t)bh * T_SEQ * HD;
  const unsigned short* Vb = Vt + (size_t)bh * HD * T_SEQ;

  auto STAGEK = [&](int tk, int s) {
    char* base = Kls + s * 16384;
    #pragma unroll
    for (int ch = 0; ch < 2; ++ch) {
      int p = (ch * 512 + tid) * 16;
      int q = p ^ (((p >> 8) & 7) << 4);
      const unsigned short* g = Kb + (size_t)(tk + (q >> 8)) * HD + ((q & 255) >> 1);
      __builtin_amdgcn_global_load_lds(
          (const __attribute__((address_space(1))) void*)g,
          (__attribute__((address_space(3))) void*)(base + (ch * 512 + (tid & 448)) * 16),
          16, 0, 0);
    }
  };
  auto STAGEV = [&](int tk, int s) {
    char* base = Vls + s * 16384;
    #pragma unroll
    for (int ch = 0; ch < 2; ++ch) {
      int p = (ch * 512 + tid) * 16;
      int q = p ^ (((p >> 7) & 7) << 4);
      const unsigned short* g = Vb + (size_t)(q >> 7) * T_SEQ + tk + ((q & 127) >> 1);
      __builtin_amdgcn_global_load_lds(
          (const __attribute__((address_space(1))) void*)g,
          (__attribute__((address_space(3))) void*)(base + (ch * 512 + (tid & 448)) * 16),
          16, 0, 0);
    }
  };

  // hoist Q (pre-roped, pre-scaled)
  bf16x8 qfr[8];
  #pragma unroll
  for (int c = 0; c < 8; ++c)
    qfr[c] = *(const bf16x8*)(Qb + (size_t)qglob * HD + c * 16 + hh * 8);

  f32x16 oacc[4];
  #pragma unroll
  for (int dt = 0; dt < 4; ++dt)
    #pragma unroll
    for (int r = 0; r < 16; ++r) oacc[dt][r] = 0.f;
  float mrun = -1e30f, lrun = 0.f;

  // prologue: tiles 0,1 -> slots 0,1
  STAGEK(0, 0); STAGEV(0, 0);
  STAGEK(64, 1); STAGEV(64, 1);
  asm volatile("s_waitcnt vmcnt(0)" ::: "memory");
  __syncthreads();

  for (int u = 0; u <= qtl; ++u) {
    if (u < qtl) {
      STAGEK((2 * u + 2) * 64, (2 * u + 2) & 3); STAGEV((2 * u + 2) * 64, (2 * u + 2) & 3);
      STAGEK((2 * u + 3) * 64, (2 * u + 3) & 3); STAGEV((2 * u + 3) * 64, (2 * u + 3) & 3);
    }
    const int jt = 2 * u + par;
    const int slot = jt & 3;

    // QK: S^T = K Q^T  (batched reads: 8 kf then 8 MFMA per t-chain)
    f32x16 sacc[2];
    #pragma unroll
    for (int t = 0; t < 2; ++t)
      #pragma unroll
      for (int r = 0; r < 16; ++r) sacc[t][r] = 0.f;
    {
      const char* kbase = Kls + slot * 16384;
      #pragma unroll
      for (int t = 0; t < 2; ++t) {
        bf16x8 kf8[8];
        #pragma unroll
        for (int s = 0; s < 8; ++s) {
          int row = t * 32 + l31;
          int byte = (row * 256 + s * 32 + hh * 16) ^ ((row & 7) << 4);
          kf8[s] = *(const bf16x8*)(kbase + byte);
        }
        __builtin_amdgcn_s_setprio(1);
        #pragma unroll
        for (int s = 0; s < 8; ++s)
          sacc[t] = __builtin_amdgcn_mfma_f32_32x32x16_bf16(kf8[s], qfr[s], sacc[t], 0, 0, 0);
        __builtin_amdgcn_s_setprio(0);
      }
    }

    if (jt >= 2 * qtl) {
      #pragma unroll
      for (int t = 0; t < 2; ++t)
        #pragma unroll
        for (int r = 0; r < 16; ++r) {
          int kg = jt * 64 + t * 32 + (r & 3) + 8 * (r >> 2) + 4 * hh;
          if (kg > qglob) sacc[t][r] = -1e30f;
        }
    }

    float pmax = sacc[0][0];
    #pragma unroll
    for (int r = 1; r < 16; ++r) pmax = fmaxf(pmax, sacc[0][r]);
    #pragma unroll
    for (int r = 0; r < 16; ++r) pmax = fmaxf(pmax, sacc[1][r]);
    pmax = fmaxf(pmax, __shfl_xor(pmax, 32));

    if (__any(pmax > mrun + 8.0f)) {   // defer-max (T13)
      float mnew = fmaxf(mrun, pmax);
      float osc = exp2f(mrun - mnew);
      lrun *= osc;
      mrun = mnew;
      #pragma unroll
      for (int r = 0; r < 16; ++r) {
        int qr = (r & 3) + 8 * (r >> 2) + 4 * hh;
        float sr = __shfl(osc, qr);
        #pragma unroll
        for (int dt = 0; dt < 4; ++dt) oacc[dt][r] *= sr;
      }
    }

    unsigned int pk[16];
    float rsum = 0.f;
    #pragma unroll
    for (int t = 0; t < 2; ++t)
      #pragma unroll
      for (int i = 0; i < 8; ++i) {
        float p0 = exp2f(sacc[t][2 * i] - mrun);
        float p1 = exp2f(sacc[t][2 * i + 1] - mrun);
        rsum += p0 + p1;
        pk[t * 8 + i] = cvt_pk_bf16(p0, p1);
      }
    rsum += __shfl_xor(rsum, 32);
    lrun += rsum;

    bf16x8 pa[4];
    #pragma unroll
    for (int c = 0; c < 4; ++c) {
      int base = (c >> 1) * 8 + (c & 1) * 4;
      unsigned int s0 = hh == 0 ? pk[base + 2] : pk[base + 0];
      unsigned int s1 = hh == 0 ? pk[base + 3] : pk[base + 1];
      unsigned int r0 = __shfl_xor((int)s0, 32);
      unsigned int r1 = __shfl_xor((int)s1, 32);
      u32x4 f;
      f[0] = hh == 0 ? pk[base + 0] : r0;
      f[1] = hh == 0 ? pk[base + 1] : r1;
      f[2] = hh == 0 ? r0 : pk[base + 2];
      f[3] = hh == 0 ? r1 : pk[base + 3];
      pa[c] = *(bf16x8*)&f;
    }

    {
      const char* vbase = Vls + slot * 16384;
      __builtin_amdgcn_s_setprio(1);
      #pragma unroll
      for (int dt = 0; dt < 4; ++dt) {
        #pragma unroll
        for (int c = 0; c < 4; ++c) {
          int row = dt * 32 + l31;
          int byte = (row * 128 + c * 32 + hh * 16) ^ ((row & 7) << 4);
          bf16x8 vf = *(const bf16x8*)(vbase + byte);
          oacc[dt] = __builtin_amdgcn_mfma_f32_32x32x16_bf16(pa[c], vf, oacc[dt], 0, 0, 0);
        }
      }
      __builtin_amdgcn_s_setprio(0);
    }

    asm volatile("s_waitcnt vmcnt(0)" ::: "memory");
    __syncthreads();
  }

  // ---- merge the two parity streams (exact LSE); buffers in DEAD K/V regions ----
  float* obuf  = (float*)alds;
  float* mlbuf = (float*)(alds + 65536);
  if (par == 1) {
    mlbuf[(wq * 64 + lane) * 2 + 0] = mrun;
    mlbuf[(wq * 64 + lane) * 2 + 1] = lrun;
    float* ob = obuf + wq * 4096;
    #pragma unroll
    for (int dt = 0; dt < 4; ++dt)
      #pragma unroll
      for (int r = 0; r < 16; ++r)
        ob[(dt * 16 + r) * 64 + lane] = oacc[dt][r];
  }
  __syncthreads();
  if (par == 0) {
    float mo = mlbuf[(wq * 64 + lane) * 2 + 0];
    float lo = mlbuf[(wq * 64 + lane) * 2 + 1];
    float mm = fmaxf(mrun, mo);
    float se = exp2f(mrun - mm), so = exp2f(mo - mm);
    float lt = lrun * se + lo * so;
    float linv = 1.0f / lt;
    const float* ob = obuf + wq * 4096;
    #pragma unroll
    for (int r = 0; r < 16; ++r) {
      int qr = (r & 3) + 8 * (r >> 2) + 4 * hh;
      float se_r = __shfl(se, qr);
      float so_r = __shfl(so, qr);
      float li_r = __shfl(linv, qr);
      int qg = q0 + wq * 32 + qr;
      size_t base = ((size_t)b * T_SEQ + qg) * CC + h * HD;
      #pragma unroll
      for (int dt = 0; dt < 4; ++dt) {
        float oo = ob[(dt * 16 + r) * 64 + lane];
        Y[base + dt * 32 + l31] = f2bf((oacc[dt][r] * se_r + oo * so_r) * li_r);
      }
    }
  }
}

extern "C" void kernel_launch(void* const* d_in, const int* in_sizes, int n_in,
                              void* d_out, int out_size, void* d_ws, size_t ws_size,
                              hipStream_t stream) {
  const float* x     = (const float*)d_in[0];
  const float* Wqkv  = (const float*)d_in[1];
  const float* Wproj = (const float*)d_in[2];
  float* out = (float*)d_out;
  char* ws = (char*)d_ws;
  const size_t MB = 1024 * 1024;
  unsigned short* WqkvT  = (unsigned short*)(ws + 0);        // 24MB; live during GEMM1
  unsigned short* WprojT = (unsigned short*)(ws + 24 * MB);  // 8MB
  unsigned short* xb     = (unsigned short*)(ws + 32 * MB);  // 16MB; dead after GEMM1
  unsigned short* y      = xb;                               // aliases xb
  unsigned short* q      = (unsigned short*)(ws + 48 * MB);  // 16MB
  unsigned short* k      = (unsigned short*)(ws + 64 * MB);  // 16MB
  unsigned short* vt     = (unsigned short*)(ws + 80 * MB);  // 16MB, written directly by GEMM1

  k_prep<<<dim3(24576), 256, 0, stream>>>(Wqkv, WqkvT, Wproj, WprojT, x, xb);
  // GEMM1: 4096 x 6144 x 2048, BM=128 BN=384 -> grid 512 (exactly 2 gens), m-major chunks
  k_gemm8<6, 1, 1><<<dim3((MM / 128) * (N3 / 384)), 512, 131072, stream>>>(
      xb, WqkvT, nullptr, q, k, vt, MM, N3, CC);
  k_rope<<<(32 * T_SEQ * 64) / 256, 256, 0, stream>>>(q, k);
  k_attn<<<dim3(512), 512, 131072, stream>>>(q, k, vt, y);
  // GEMM2: 4096 x 2048 x 2048, BM=128 BN=256 -> grid 256 (exactly 1/CU), n-major chunks
  k_gemm8<4, 0, 0><<<dim3((MM / 128) * (CC / 256)), 512, 98304, stream>>>(
      y, WprojT, out, nullptr, nullptr, nullptr, MM, CC, CC);
}